// Round 4
// baseline (1004.448 us; speedup 1.0000x reference)
//
#include <hip/hip_runtime.h>
#include <math.h>

#define B_ 2
#define S_ 1024
#define D_ 512
#define H_ 8
#define P_ 16
#define DH_ 64
#define HP3_ 384
#define CONCAT_ 896
#define CUTOFF 15.0f
#define SCALE_ 0.125f   // DH^-0.5 = 1/8

// ---------------------------------------------------------------- reductions
__device__ __forceinline__ float waveReduceSum(float v) {
#pragma unroll
    for (int o = 32; o; o >>= 1) v += __shfl_down(v, o, 64);
    return v;
}
__device__ __forceinline__ float waveReduceMax(float v) {
#pragma unroll
    for (int o = 32; o; o >>= 1) v = fmaxf(v, __shfl_down(v, o, 64));
    return v;
}

// ---------------------------------------------------------------- kernel 1: LN(x) -> xn
__global__ __launch_bounds__(256) void ln1_kernel(
    const float* __restrict__ x, const float* __restrict__ g,
    const float* __restrict__ b, float* __restrict__ xn) {
    const int row = blockIdx.x;           // b*S + s  (2048 rows)
    const int t = threadIdx.x;
    const float* xr = x + row * D_;
    float x0 = xr[t], x1 = xr[t + 256];
    __shared__ float red[4];
    float s = waveReduceSum(x0 + x1);
    int lane = t & 63, wid = t >> 6;
    if (lane == 0) red[wid] = s;
    __syncthreads();
    float mean = (red[0] + red[1] + red[2] + red[3]) * (1.0f / D_);
    __syncthreads();
    float d0 = x0 - mean, d1 = x1 - mean;
    float v = waveReduceSum(d0 * d0 + d1 * d1);
    if (lane == 0) red[wid] = v;
    __syncthreads();
    float var = (red[0] + red[1] + red[2] + red[3]) * (1.0f / D_);
    float rs = rsqrtf(var + 1e-5f);
    xn[row * D_ + t]       = d0 * rs * g[t] + b[t];
    xn[row * D_ + t + 256] = d1 * rs * g[t + 256] + b[t + 256];
}

// ---------------------------------------------------------------- kernel 2: projections GEMM
__global__ __launch_bounds__(256) void proj_kernel(
    const float* __restrict__ xn, const float* __restrict__ coords,
    const float* __restrict__ Wq, const float* __restrict__ Wk, const float* __restrict__ Wv,
    const float* __restrict__ Wqp, const float* __restrict__ bqp,
    const float* __restrict__ Wkp, const float* __restrict__ bkp,
    const float* __restrict__ Wvp, const float* __restrict__ bvp,
    float* __restrict__ q, float* __restrict__ k, float* __restrict__ v,
    float* __restrict__ qp, float* __restrict__ kp, float* __restrict__ vp) {
    const int tid = threadIdx.x;
    const int rowBase = blockIdx.y * 64;
    const int colBase = blockIdx.x * 64;

    const float* Wseg; int ldw, segBase, segId;
    if      (colBase < 512)  { Wseg = Wq;  ldw = D_;   segBase = 0;    segId = 0; }
    else if (colBase < 1024) { Wseg = Wk;  ldw = D_;   segBase = 512;  segId = 1; }
    else if (colBase < 1536) { Wseg = Wv;  ldw = D_;   segBase = 1024; segId = 2; }
    else if (colBase < 1920) { Wseg = Wqp; ldw = HP3_; segBase = 1536; segId = 3; }
    else if (colBase < 2304) { Wseg = Wkp; ldw = HP3_; segBase = 1920; segId = 4; }
    else                     { Wseg = Wvp; ldw = HP3_; segBase = 2304; segId = 5; }
    const int segc0 = colBase - segBase;

    __shared__ float As[16][65];
    __shared__ float Bs[16][64];
    const int tx = tid & 15, ty = tid >> 4;

    float acc[4][4];
#pragma unroll
    for (int i = 0; i < 4; i++)
#pragma unroll
        for (int j = 0; j < 4; j++) acc[i][j] = 0.f;

    for (int k0 = 0; k0 < D_; k0 += 16) {
#pragma unroll
        for (int i = 0; i < 4; i++) {
            int e = tid + i * 256;
            int r = e >> 4, kk = e & 15;
            As[kk][r] = xn[(rowBase + r) * D_ + k0 + kk];
            int c = e & 63, kb = e >> 6;
            Bs[kb][c] = Wseg[(k0 + kb) * ldw + segc0 + c];
        }
        __syncthreads();
#pragma unroll
        for (int kk = 0; kk < 16; kk++) {
            float a[4], bb[4];
#pragma unroll
            for (int i = 0; i < 4; i++) a[i] = As[kk][ty * 4 + i];
#pragma unroll
            for (int j = 0; j < 4; j++) bb[j] = Bs[kk][tx * 4 + j];
#pragma unroll
            for (int i = 0; i < 4; i++)
#pragma unroll
                for (int j = 0; j < 4; j++) acc[i][j] = fmaf(a[i], bb[j], acc[i][j]);
        }
        __syncthreads();
    }

#pragma unroll
    for (int i = 0; i < 4; i++) {
        int r = rowBase + ty * 4 + i;
#pragma unroll
        for (int j = 0; j < 4; j++) {
            int lc = segc0 + tx * 4 + j;
            float val = acc[i][j];
            switch (segId) {
                case 0: q[r * D_ + lc] = val; break;
                case 1: k[r * D_ + lc] = val; break;
                case 2: v[r * D_ + lc] = val; break;
                case 3: qp[r * HP3_ + lc] = val + bqp[lc] + coords[r * 3 + lc % 3]; break;
                case 4: kp[r * HP3_ + lc] = val + bkp[lc] + coords[r * 3 + lc % 3]; break;
                case 5: vp[r * HP3_ + lc] = val + bvp[lc]; break;
            }
        }
    }
}

// ---------------------------------------------------------------- kernel 3: kn2 = sum(kp^2) per (b,s,h)
__global__ __launch_bounds__(256) void kn2_kernel(
    const float* __restrict__ kp, float* __restrict__ kn2) {
    int idx = blockIdx.x * 256 + threadIdx.x;   // B*S*H = 16384
    const float* p = kp + idx * 48;
    float s = 0.f;
#pragma unroll
    for (int i = 0; i < 48; i++) s = fmaf(p[i], p[i], s);
    kn2[idx] = s;
}

// ---------------------------------------------------------------- kernel 4: fused attention with neighbor compaction
// One block per (q-row, head, batch). Masked keys (dist>=15) contribute exactly 0
// (reference logit is exactly -1e9 -> exp underflows to 0 in fp32), so we compact
// the ~23% active keys and only pay for those.
__global__ __launch_bounds__(256) void attn_kernel(
    const float* __restrict__ q, const float* __restrict__ k, const float* __restrict__ v,
    const float* __restrict__ qp, const float* __restrict__ kp, const float* __restrict__ vp,
    const float* __restrict__ kn2, const float* __restrict__ coords,
    const float* __restrict__ Wd1, const float* __restrict__ bd1,
    const float* __restrict__ Wd2, const float* __restrict__ bd2,
    float* __restrict__ attn_out) {
    const int qi = blockIdx.x, h = blockIdx.y, b = blockIdx.z;
    const int tid = threadIdx.x;
    const int lane = tid & 63, wid = tid >> 6;
    const int rowQ = b * S_ + qi;

    __shared__ float sQ[64], sQP[48], sW1[32], sB1[32], sW2[32];
    __shared__ unsigned short sIdx[1024];
    __shared__ float sDist[1024];
    __shared__ float sW[1024];
    __shared__ float red[4];
    __shared__ float sAcc[112];
    __shared__ int sCnt;

    if (tid < 64)       sQ[tid] = q[rowQ * D_ + h * 64 + tid];
    else if (tid < 112) sQP[tid - 64] = qp[rowQ * HP3_ + h * 48 + (tid - 64)];
    else if (tid < 144) sW1[tid - 112] = Wd1[tid - 112];
    else if (tid < 176) sB1[tid - 144] = bd1[tid - 144];
    else if (tid < 208) sW2[tid - 176] = Wd2[(tid - 176) * H_ + h];
    else if (tid == 255) sCnt = 0;
    const float cq0 = coords[rowQ * 3], cq1 = coords[rowQ * 3 + 1], cq2 = coords[rowQ * 3 + 2];
    const float bd2h = bd2[h];
    __syncthreads();

    float qn2 = 0.f;
#pragma unroll
    for (int i = 0; i < 48; i++) qn2 = fmaf(sQP[i], sQP[i], qn2);

    // ---- phase 0: dist + compaction (ballot + wave-prefix + one LDS atomic per wave)
#pragma unroll
    for (int j = 0; j < 4; j++) {
        const int kk = tid + j * 256;
        const int rowK = b * S_ + kk;
        float dx = cq0 - coords[rowK * 3];
        float dy = cq1 - coords[rowK * 3 + 1];
        float dz = cq2 - coords[rowK * 3 + 2];
        float dist = sqrtf(fmaf(dx, dx, fmaf(dy, dy, dz * dz)));
        bool act = dist < CUTOFF;
        unsigned long long mk = __ballot(act);
        int wcnt = __popcll(mk);
        int base = 0;
        if (lane == 0 && wcnt) base = atomicAdd(&sCnt, wcnt);
        base = __shfl(base, 0, 64);
        if (act) {
            int pos = base + __popcll(mk & ((1ull << lane) - 1ull));
            sIdx[pos] = (unsigned short)kk;
            sDist[pos] = dist;
        }
    }
    __syncthreads();
    const int nA = sCnt;   // >= 1 (self is always within cutoff)

    // ---- phase 1: logits over compacted keys (full lane utilization)
    float m = -3.0e38f;
    for (int i = tid; i < nA; i += 256) {
        const int rowK = b * S_ + sIdx[i];
        const float4* kr = (const float4*)(k + (size_t)rowK * D_ + h * 64);
        float dot = 0.f;
#pragma unroll
        for (int j = 0; j < 16; j++) {
            float4 kv = kr[j];
            float4 qv = *(const float4*)(sQ + j * 4);
            dot = fmaf(qv.x, kv.x, fmaf(qv.y, kv.y, fmaf(qv.z, kv.z, fmaf(qv.w, kv.w, dot))));
        }
        const float4* kpr = (const float4*)(kp + (size_t)rowK * HP3_ + h * 48);
        float pd = 0.f;
#pragma unroll
        for (int j = 0; j < 12; j++) {
            float4 kv = kpr[j];
            float4 qv = *(const float4*)(sQP + j * 4);
            pd = fmaf(qv.x, kv.x, fmaf(qv.y, kv.y, fmaf(qv.z, kv.z, fmaf(qv.w, kv.w, pd))));
        }
        float dist = sDist[i];
        float bias = bd2h;
#pragma unroll
        for (int jj = 0; jj < 32; jj++) {
            float hd = fmaf(dist, sW1[jj], sB1[jj]);
            bias = fmaf(fmaxf(hd, 0.f), sW2[jj], bias);
        }
        float lg = fmaf(SCALE_, dot, pd) - 0.5f * (qn2 + kn2[rowK * H_ + h]) + bias;
        sW[i] = lg;
        m = fmaxf(m, lg);
    }

    // ---- phase 2: softmax over compacted list
    m = waveReduceMax(m);
    if (lane == 0) red[wid] = m;
    __syncthreads();
    m = fmaxf(fmaxf(red[0], red[1]), fmaxf(red[2], red[3]));
    __syncthreads();
    float psum = 0.f;
    for (int i = tid; i < nA; i += 256) {
        float e = __expf(sW[i] - m);
        sW[i] = e;
        psum += e;
    }
    psum = waveReduceSum(psum);
    if (lane == 0) red[wid] = psum;
    __syncthreads();
    const float inv = 1.0f / (red[0] + red[1] + red[2] + red[3]);

    // ---- phase 3: weighted sums over compacted keys
    // 2 groups of 128 threads; group g takes keys i = g, g+2, ... (2-way unrolled)
    const int g = tid >> 7, d = tid & 127;
    float acc0 = 0.f, acc1 = 0.f;
    if (d < 112) {
        const float* vb; int stride;
        if (d < 64) { vb = v  + (size_t)b * S_ * D_   + h * 64 + d;        stride = D_;   }
        else        { vb = vp + (size_t)b * S_ * HP3_ + h * 48 + (d - 64); stride = HP3_; }
        int i = g;
        for (; i + 2 < nA; i += 4) {
            acc0 = fmaf(sW[i],     vb[(size_t)sIdx[i]     * stride], acc0);
            acc1 = fmaf(sW[i + 2], vb[(size_t)sIdx[i + 2] * stride], acc1);
        }
        if (i < nA) acc0 = fmaf(sW[i], vb[(size_t)sIdx[i] * stride], acc0);
        acc0 += acc1;
    }
    if (g == 1 && d < 112) sAcc[d] = acc0;
    __syncthreads();
    if (g == 0 && d < 112) {
        float tot = (acc0 + sAcc[d]) * inv;
        float* outr = attn_out + (size_t)rowQ * CONCAT_;
        if (d < 64) outr[h * 64 + d] = tot;
        else        outr[512 + h * 48 + (d - 64)] = tot;
    }
}

// ---------------------------------------------------------------- kernel 5: out proj + residual + LN2 + coord update
__global__ __launch_bounds__(256) void out_kernel(
    const float* __restrict__ attn_out, const float* __restrict__ x,
    const float* __restrict__ coords,
    const float* __restrict__ Wo, const float* __restrict__ bo,
    const float* __restrict__ g2, const float* __restrict__ b2,
    float* __restrict__ out, float* __restrict__ coords_out) {
    const int row = blockIdx.x;
    const int t = threadIdx.x;
    __shared__ float sIn[CONCAT_];
    __shared__ float red[4];
    __shared__ float credp[2][3];

    const float* ar = attn_out + (size_t)row * CONCAT_;
    sIn[t] = ar[t]; sIn[t + 256] = ar[t + 256]; sIn[t + 512] = ar[t + 512];
    if (t < 128) sIn[t + 768] = ar[t + 768];
    __syncthreads();

    float c0 = 0.f, c1 = 0.f, c2 = 0.f;
    if (t < 128) { c0 = sIn[512 + t * 3]; c1 = sIn[512 + t * 3 + 1]; c2 = sIn[512 + t * 3 + 2]; }
#pragma unroll
    for (int o = 32; o; o >>= 1) {
        c0 += __shfl_down(c0, o, 64);
        c1 += __shfl_down(c1, o, 64);
        c2 += __shfl_down(c2, o, 64);
    }
    if (t < 128 && (t & 63) == 0) {
        credp[t >> 6][0] = c0; credp[t >> 6][1] = c1; credp[t >> 6][2] = c2;
    }
    __syncthreads();
    if (t < 3) {
        float s = credp[0][t] + credp[1][t];
        coords_out[row * 3 + t] = coords[row * 3 + t] + 0.1f * s * (1.0f / 128.f);
    }

    float a0 = bo[t], a1 = bo[t + 256];
    for (int i = 0; i < CONCAT_; i++) {
        float xi = sIn[i];
        a0 = fmaf(xi, Wo[i * D_ + t], a0);
        a1 = fmaf(xi, Wo[i * D_ + t + 256], a1);
    }
    float y0 = x[(size_t)row * D_ + t] + a0;
    float y1 = x[(size_t)row * D_ + t + 256] + a1;

    float s = waveReduceSum(y0 + y1);
    int lane = t & 63, wid = t >> 6;
    if (lane == 0) red[wid] = s;
    __syncthreads();
    float mean = (red[0] + red[1] + red[2] + red[3]) * (1.0f / D_);
    __syncthreads();
    float d0 = y0 - mean, d1 = y1 - mean;
    float vv = waveReduceSum(d0 * d0 + d1 * d1);
    if (lane == 0) red[wid] = vv;
    __syncthreads();
    float var = (red[0] + red[1] + red[2] + red[3]) * (1.0f / D_);
    float rs = rsqrtf(var + 1e-5f);
    out[(size_t)row * D_ + t]       = d0 * rs * g2[t] + b2[t];
    out[(size_t)row * D_ + t + 256] = d1 * rs * g2[t + 256] + b2[t + 256];
}

// ---------------------------------------------------------------- launch
extern "C" void kernel_launch(void* const* d_in, const int* in_sizes, int n_in,
                              void* d_out, int out_size, void* d_ws, size_t ws_size,
                              hipStream_t stream) {
    const float* x      = (const float*)d_in[0];
    const float* coords = (const float*)d_in[1];
    const float* Wq     = (const float*)d_in[2];
    const float* Wk     = (const float*)d_in[3];
    const float* Wv     = (const float*)d_in[4];
    const float* Wqp    = (const float*)d_in[5];
    const float* bqp    = (const float*)d_in[6];
    const float* Wkp    = (const float*)d_in[7];
    const float* bkp    = (const float*)d_in[8];
    const float* Wvp    = (const float*)d_in[9];
    const float* bvp    = (const float*)d_in[10];
    const float* Wd1    = (const float*)d_in[11];
    const float* bd1    = (const float*)d_in[12];
    const float* Wd2    = (const float*)d_in[13];
    const float* bd2    = (const float*)d_in[14];
    const float* Wo     = (const float*)d_in[15];
    const float* bo     = (const float*)d_in[16];
    const float* g1     = (const float*)d_in[17];
    const float* b1     = (const float*)d_in[18];
    const float* g2     = (const float*)d_in[19];
    const float* b2     = (const float*)d_in[20];

    float* out        = (float*)d_out;
    float* coords_out = (float*)d_out + (size_t)B_ * S_ * D_;

    float* ws = (float*)d_ws;
    const size_t NROW = (size_t)B_ * S_;
    float* xn   = ws;
    float* q    = xn   + NROW * D_;
    float* k    = q    + NROW * D_;
    float* v    = k    + NROW * D_;
    float* qp   = v    + NROW * D_;
    float* kp   = qp   + NROW * HP3_;
    float* vp   = kp   + NROW * HP3_;
    float* kn2  = vp   + NROW * HP3_;
    float* aout = kn2  + NROW * H_;

    ln1_kernel<<<NROW, 256, 0, stream>>>(x, g1, b1, xn);

    dim3 pgrid(2688 / 64, 2048 / 64);
    proj_kernel<<<pgrid, 256, 0, stream>>>(xn, coords, Wq, Wk, Wv,
                                           Wqp, bqp, Wkp, bkp, Wvp, bvp,
                                           q, k, v, qp, kp, vp);

    kn2_kernel<<<(NROW * H_) / 256, 256, 0, stream>>>(kp, kn2);

    dim3 agrid(S_, H_, B_);
    attn_kernel<<<agrid, 256, 0, stream>>>(q, k, v, qp, kp, vp, kn2, coords,
                                           Wd1, bd1, Wd2, bd2, aout);

    out_kernel<<<NROW, 256, 0, stream>>>(aout, x, coords, Wo, bo, g2, b2,
                                         out, coords_out);
}

// Round 5
// 579.309 us; speedup vs baseline: 1.7339x; 1.7339x over previous
//
#include <hip/hip_runtime.h>
#include <math.h>

#define B_ 2
#define S_ 1024
#define D_ 512
#define H_ 8
#define P_ 16
#define DH_ 64
#define HP3_ 384
#define CONCAT_ 896
#define CUTOFF 15.0f
#define SCALE_ 0.125f   // DH^-0.5 = 1/8
#define QT 32
#define KT 64

// ---------------------------------------------------------------- reductions
__device__ __forceinline__ float waveReduceSum(float v) {
#pragma unroll
    for (int o = 32; o; o >>= 1) v += __shfl_down(v, o, 64);
    return v;
}
__device__ __forceinline__ float waveReduceMax(float v) {
#pragma unroll
    for (int o = 32; o; o >>= 1) v = fmaxf(v, __shfl_down(v, o, 64));
    return v;
}

// ---------------------------------------------------------------- kernel 1: LN(x) -> xn
__global__ __launch_bounds__(256) void ln1_kernel(
    const float* __restrict__ x, const float* __restrict__ g,
    const float* __restrict__ b, float* __restrict__ xn) {
    const int row = blockIdx.x;           // b*S + s  (2048 rows)
    const int t = threadIdx.x;
    const float* xr = x + row * D_;
    float x0 = xr[t], x1 = xr[t + 256];
    __shared__ float red[4];
    float s = waveReduceSum(x0 + x1);
    int lane = t & 63, wid = t >> 6;
    if (lane == 0) red[wid] = s;
    __syncthreads();
    float mean = (red[0] + red[1] + red[2] + red[3]) * (1.0f / D_);
    __syncthreads();
    float d0 = x0 - mean, d1 = x1 - mean;
    float v = waveReduceSum(d0 * d0 + d1 * d1);
    if (lane == 0) red[wid] = v;
    __syncthreads();
    float var = (red[0] + red[1] + red[2] + red[3]) * (1.0f / D_);
    float rs = rsqrtf(var + 1e-5f);
    xn[row * D_ + t]       = d0 * rs * g[t] + b[t];
    xn[row * D_ + t + 256] = d1 * rs * g[t + 256] + b[t + 256];
}

// ---------------------------------------------------------------- kernel 2: projections GEMM
__global__ __launch_bounds__(256) void proj_kernel(
    const float* __restrict__ xn, const float* __restrict__ coords,
    const float* __restrict__ Wq, const float* __restrict__ Wk, const float* __restrict__ Wv,
    const float* __restrict__ Wqp, const float* __restrict__ bqp,
    const float* __restrict__ Wkp, const float* __restrict__ bkp,
    const float* __restrict__ Wvp, const float* __restrict__ bvp,
    float* __restrict__ q, float* __restrict__ k, float* __restrict__ v,
    float* __restrict__ qp, float* __restrict__ kp, float* __restrict__ vp) {
    const int tid = threadIdx.x;
    const int rowBase = blockIdx.y * 64;
    const int colBase = blockIdx.x * 64;

    const float* Wseg; int ldw, segBase, segId;
    if      (colBase < 512)  { Wseg = Wq;  ldw = D_;   segBase = 0;    segId = 0; }
    else if (colBase < 1024) { Wseg = Wk;  ldw = D_;   segBase = 512;  segId = 1; }
    else if (colBase < 1536) { Wseg = Wv;  ldw = D_;   segBase = 1024; segId = 2; }
    else if (colBase < 1920) { Wseg = Wqp; ldw = HP3_; segBase = 1536; segId = 3; }
    else if (colBase < 2304) { Wseg = Wkp; ldw = HP3_; segBase = 1920; segId = 4; }
    else                     { Wseg = Wvp; ldw = HP3_; segBase = 2304; segId = 5; }
    const int segc0 = colBase - segBase;

    __shared__ float As[16][65];
    __shared__ float Bs[16][64];
    const int tx = tid & 15, ty = tid >> 4;

    float acc[4][4];
#pragma unroll
    for (int i = 0; i < 4; i++)
#pragma unroll
        for (int j = 0; j < 4; j++) acc[i][j] = 0.f;

    for (int k0 = 0; k0 < D_; k0 += 16) {
#pragma unroll
        for (int i = 0; i < 4; i++) {
            int e = tid + i * 256;
            int r = e >> 4, kk = e & 15;
            As[kk][r] = xn[(rowBase + r) * D_ + k0 + kk];
            int c = e & 63, kb = e >> 6;
            Bs[kb][c] = Wseg[(k0 + kb) * ldw + segc0 + c];
        }
        __syncthreads();
#pragma unroll
        for (int kk = 0; kk < 16; kk++) {
            float a[4], bb[4];
#pragma unroll
            for (int i = 0; i < 4; i++) a[i] = As[kk][ty * 4 + i];
#pragma unroll
            for (int j = 0; j < 4; j++) bb[j] = Bs[kk][tx * 4 + j];
#pragma unroll
            for (int i = 0; i < 4; i++)
#pragma unroll
                for (int j = 0; j < 4; j++) acc[i][j] = fmaf(a[i], bb[j], acc[i][j]);
        }
        __syncthreads();
    }

#pragma unroll
    for (int i = 0; i < 4; i++) {
        int r = rowBase + ty * 4 + i;
#pragma unroll
        for (int j = 0; j < 4; j++) {
            int lc = segc0 + tx * 4 + j;
            float val = acc[i][j];
            switch (segId) {
                case 0: q[r * D_ + lc] = val; break;
                case 1: k[r * D_ + lc] = val; break;
                case 2: v[r * D_ + lc] = val; break;
                case 3: qp[r * HP3_ + lc] = val + bqp[lc] + coords[r * 3 + lc % 3]; break;
                case 4: kp[r * HP3_ + lc] = val + bkp[lc] + coords[r * 3 + lc % 3]; break;
                case 5: vp[r * HP3_ + lc] = val + bvp[lc]; break;
            }
        }
    }
}

// ---------------------------------------------------------------- kernel 3: kn2 = sum(kp^2) per (b,s,h)
__global__ __launch_bounds__(256) void kn2_kernel(
    const float* __restrict__ kp, float* __restrict__ kn2) {
    int idx = blockIdx.x * 256 + threadIdx.x;   // B*S*H = 16384
    const float* p = kp + idx * 48;
    float s = 0.f;
#pragma unroll
    for (int i = 0; i < 48; i++) s = fmaf(p[i], p[i], s);
    kn2[idx] = s;
}

// ---------------------------------------------------------------- kernel 4: dense flash attention, q-tiled
// Block = (q-tile of 32, head, batch). K/V tiles staged in LDS, reused by all
// 32 q rows -> ~14x less cache traffic than per-q gathering. Online softmax.
// Masked pairs get exactly -1e9 (exp -> 0); all-masked early tiles self-correct
// via the flash rescale factor exp(m_old - m_new) = 0.
__global__ __launch_bounds__(256) void attn_kernel(
    const float* __restrict__ q, const float* __restrict__ k, const float* __restrict__ v,
    const float* __restrict__ qp, const float* __restrict__ kp, const float* __restrict__ vp,
    const float* __restrict__ kn2, const float* __restrict__ coords,
    const float* __restrict__ Wd1, const float* __restrict__ bd1,
    const float* __restrict__ Wd2, const float* __restrict__ bd2,
    float* __restrict__ attn_out) {
    const int qt = blockIdx.x, h = blockIdx.y, b = blockIdx.z;
    const int tid = threadIdx.x;
    const int qpair = tid >> 4;        // 0..15 : this thread's 2 q rows
    const int sub   = tid & 15;        // logits: key-quad; PV: dim-group
    const int q0 = qpair * 2, q1 = q0 + 1;
    const int qbase = qt * QT;

    // padded strides (65/49/113/33) keep wave conflicts <= 2-way
    __shared__ float sQ[QT][65];
    __shared__ float sQP[QT][49];
    __shared__ float sBuf[7296];       // K:[64][65]@0 + KP:[64][49]@4160  |  V:[64][113]
    __shared__ float sWt[KT][33];      // exp-weights transposed [key][q]
    __shared__ float sCq[QT * 3], sCk[KT * 3];
    __shared__ float sKn2[KT], sQn2[QT];
    __shared__ float sM[QT], sL[QT], sTm[QT];
    __shared__ float sW1[32], sB1[32], sW2h[32];

    // ---- stage Q-side (once)
    {
        const size_t bq = (size_t)(b * S_ + qbase);
#pragma unroll
        for (int i = 0; i < 2; i++) {
            int f4 = tid + i * 256;               // 512 float4 = 32x64
            int r = f4 >> 4, c = f4 & 15;
            float4 t = *(const float4*)(q + (bq + r) * D_ + h * DH_ + c * 4);
            sQ[r][c*4+0]=t.x; sQ[r][c*4+1]=t.y; sQ[r][c*4+2]=t.z; sQ[r][c*4+3]=t.w;
        }
#pragma unroll
        for (int i = 0; i < 2; i++) {
            int f4 = tid + i * 256;               // 384 float4 = 32x48
            if (f4 < 384) {
                int r = f4 / 12, c = f4 % 12;
                float4 t = *(const float4*)(qp + (bq + r) * HP3_ + h * 48 + c * 4);
                sQP[r][c*4+0]=t.x; sQP[r][c*4+1]=t.y; sQP[r][c*4+2]=t.z; sQP[r][c*4+3]=t.w;
            }
        }
        if (tid < QT * 3) sCq[tid] = coords[bq * 3 + tid];
        if (tid < 32) sW1[tid] = Wd1[tid];
        else if (tid < 64) sB1[tid - 32] = bd1[tid - 32];
        else if (tid < 96) sW2h[tid - 64] = Wd2[(tid - 64) * H_ + h];
        if (tid >= 224) { int t2 = tid - 224; sM[t2] = -3.0e38f; sL[t2] = 0.f; }
    }
    __syncthreads();
    if (tid < QT) {
        float s = 0.f;
#pragma unroll
        for (int i = 0; i < 48; i++) s = fmaf(sQP[tid][i], sQP[tid][i], s);
        sQn2[tid] = s;
    }
    const float bd2h = bd2[h];

    float o0[7] = {0,0,0,0,0,0,0}, o1[7] = {0,0,0,0,0,0,0};
    const int kb = sub * 4;   // logits: 4 keys
    const int db = sub * 7;   // PV: 7 of 112 output dims

    for (int kt = 0; kt < S_ / KT; kt++) {
        const int k0 = kt * KT;
        const size_t bk = (size_t)(b * S_ + k0);
        // ---- stage K tile (sQn2 from pre-loop code is covered by SYNC-K)
#pragma unroll
        for (int i = 0; i < 4; i++) {
            int f4 = tid + i * 256;               // 1024 float4 = 64x64
            int r = f4 >> 4, c = f4 & 15;
            float4 t = *(const float4*)(k + (bk + r) * D_ + h * DH_ + c * 4);
            float* dst = &sBuf[r * 65 + c * 4];
            dst[0]=t.x; dst[1]=t.y; dst[2]=t.z; dst[3]=t.w;
        }
#pragma unroll
        for (int i = 0; i < 3; i++) {
            int f4 = tid + i * 256;               // 768 float4 = 64x48
            int r = f4 / 12, c = f4 % 12;
            float4 t = *(const float4*)(kp + (bk + r) * HP3_ + h * 48 + c * 4);
            float* dst = &sBuf[4160 + r * 49 + c * 4];
            dst[0]=t.x; dst[1]=t.y; dst[2]=t.z; dst[3]=t.w;
        }
        if (tid < KT) sKn2[tid] = kn2[(bk + tid) * H_ + h];
        if (tid < KT * 3) sCk[tid] = coords[bk * 3 + tid];
        __syncthreads();                          // SYNC-K

        // ---- pair distances (2q x 4k)
        float ds0[4], ds1[4];
        {
            const float qx0 = sCq[q0*3], qy0 = sCq[q0*3+1], qz0 = sCq[q0*3+2];
            const float qx1 = sCq[q1*3], qy1 = sCq[q1*3+1], qz1 = sCq[q1*3+2];
#pragma unroll
            for (int j = 0; j < 4; j++) {
                int kk = kb + j;
                float kx = sCk[kk*3], ky = sCk[kk*3+1], kz = sCk[kk*3+2];
                float dx = qx0-kx, dy = qy0-ky, dz = qz0-kz;
                ds0[j] = sqrtf(fmaf(dx,dx,fmaf(dy,dy,dz*dz)));
                dx = qx1-kx; dy = qy1-ky; dz = qz1-kz;
                ds1[j] = sqrtf(fmaf(dx,dx,fmaf(dy,dy,dz*dz)));
            }
        }
        // ---- dist-MLP bias (pd will be folded into the same accumulator)
        float bias0[4], bias1[4];
#pragma unroll
        for (int j = 0; j < 4; j++) { bias0[j] = bd2h; bias1[j] = bd2h; }
#pragma unroll 4
        for (int jj = 0; jj < 32; jj++) {
            float w1 = sW1[jj], bb = sB1[jj], w2 = sW2h[jj];
#pragma unroll
            for (int j = 0; j < 4; j++) {
                float h0 = fmaf(ds0[j], w1, bb);
                float h1 = fmaf(ds1[j], w1, bb);
                bias0[j] = fmaf(fmaxf(h0, 0.f), w2, bias0[j]);
                bias1[j] = fmaf(fmaxf(h1, 0.f), w2, bias1[j]);
            }
        }
        // ---- qk dot (64) ; 2q x 4k register micro-tile
        float d0a[4] = {0,0,0,0}, d1a[4] = {0,0,0,0};
#pragma unroll 8
        for (int d = 0; d < 64; d++) {
            float a0 = sQ[q0][d], a1 = sQ[q1][d];
#pragma unroll
            for (int j = 0; j < 4; j++) {
                float bv = sBuf[(kb + j) * 65 + d];
                d0a[j] = fmaf(a0, bv, d0a[j]);
                d1a[j] = fmaf(a1, bv, d1a[j]);
            }
        }
        // ---- point dot (48), folded into bias accumulators
#pragma unroll 8
        for (int d = 0; d < 48; d++) {
            float a0 = sQP[q0][d], a1 = sQP[q1][d];
#pragma unroll
            for (int j = 0; j < 4; j++) {
                float bv = sBuf[4160 + (kb + j) * 49 + d];
                bias0[j] = fmaf(a0, bv, bias0[j]);
                bias1[j] = fmaf(a1, bv, bias1[j]);
            }
        }
        // ---- logits + mask
        const float qn20 = sQn2[q0], qn21 = sQn2[q1];
        float lg0[4], lg1[4];
#pragma unroll
        for (int j = 0; j < 4; j++) {
            float kn = sKn2[kb + j];
            float v0 = fmaf(SCALE_, d0a[j], bias0[j]) - 0.5f * (qn20 + kn);
            float v1 = fmaf(SCALE_, d1a[j], bias1[j]) - 0.5f * (qn21 + kn);
            lg0[j] = (ds0[j] < CUTOFF) ? v0 : -1e9f;
            lg1[j] = (ds1[j] < CUTOFF) ? v1 : -1e9f;
        }
        // ---- tile row-max across the 16 key-quads (lanes of same qpair are 16 consecutive)
        float t0 = fmaxf(fmaxf(lg0[0], lg0[1]), fmaxf(lg0[2], lg0[3]));
        float t1 = fmaxf(fmaxf(lg1[0], lg1[1]), fmaxf(lg1[2], lg1[3]));
#pragma unroll
        for (int off = 1; off < 16; off <<= 1) {
            t0 = fmaxf(t0, __shfl_xor(t0, off, 16));
            t1 = fmaxf(t1, __shfl_xor(t1, off, 16));
        }
        if (sub == 0) { sTm[q0] = t0; sTm[q1] = t1; }
        __syncthreads();                          // SYNC-A1
        // ---- online softmax update
        const float m0o = sM[q0], m1o = sM[q1];
        const float nm0 = fmaxf(m0o, sTm[q0]), nm1 = fmaxf(m1o, sTm[q1]);
        const float sc0 = __expf(m0o - nm0), sc1 = __expf(m1o - nm1);
        float ps0 = 0.f, ps1 = 0.f;
#pragma unroll
        for (int j = 0; j < 4; j++) {
            float w0 = __expf(lg0[j] - nm0);
            float w1 = __expf(lg1[j] - nm1);
            sWt[kb + j][q0] = w0; sWt[kb + j][q1] = w1;
            ps0 += w0; ps1 += w1;
        }
#pragma unroll
        for (int off = 1; off < 16; off <<= 1) {
            ps0 += __shfl_xor(ps0, off, 16);
            ps1 += __shfl_xor(ps1, off, 16);
        }
        __syncthreads();                          // SYNC-A2 (sM reads + sWt writes done)
        if (sub == 0) {
            sM[q0] = nm0; sM[q1] = nm1;
            sL[q0] = sL[q0] * sc0 + ps0;
            sL[q1] = sL[q1] * sc1 + ps1;
        }
        // ---- stage V tile (reuses sBuf; logit reads finished before SYNC-A2)
#pragma unroll
        for (int i = 0; i < 4; i++) {
            int f4 = tid + i * 256;
            int r = f4 >> 4, c = f4 & 15;
            float4 t = *(const float4*)(v + (bk + r) * D_ + h * DH_ + c * 4);
            float* dst = &sBuf[r * 113 + c * 4];
            dst[0]=t.x; dst[1]=t.y; dst[2]=t.z; dst[3]=t.w;
        }
#pragma unroll
        for (int i = 0; i < 3; i++) {
            int f4 = tid + i * 256;
            int r = f4 / 12, c = f4 % 12;
            float4 t = *(const float4*)(vp + (bk + r) * HP3_ + h * 48 + c * 4);
            float* dst = &sBuf[r * 113 + 64 + c * 4];
            dst[0]=t.x; dst[1]=t.y; dst[2]=t.z; dst[3]=t.w;
        }
        __syncthreads();                          // SYNC-B
        // ---- PV accumulate (2q x 7dims per thread)
#pragma unroll
        for (int j = 0; j < 7; j++) { o0[j] *= sc0; o1[j] *= sc1; }
#pragma unroll 4
        for (int kk = 0; kk < KT; kk++) {
            float w0 = sWt[kk][q0], w1 = sWt[kk][q1];
            const float* vr = &sBuf[kk * 113 + db];
#pragma unroll
            for (int j = 0; j < 7; j++) {
                float vv = vr[j];
                o0[j] = fmaf(w0, vv, o0[j]);
                o1[j] = fmaf(w1, vv, o1[j]);
            }
        }
        __syncthreads();                          // SYNC-C (before next K-stage overwrites sBuf)
    }

    // ---- epilogue: normalize + write
    const float il0 = 1.0f / sL[q0], il1 = 1.0f / sL[q1];
    const size_t r0 = (size_t)(b * S_ + qbase + q0) * CONCAT_;
    const size_t r1 = (size_t)(b * S_ + qbase + q1) * CONCAT_;
#pragma unroll
    for (int j = 0; j < 7; j++) {
        int d = db + j;
        int off = (d < 64) ? (h * 64 + d) : (512 + h * 48 + (d - 64));
        attn_out[r0 + off] = o0[j] * il0;
        attn_out[r1 + off] = o1[j] * il1;
    }
}

// ---------------------------------------------------------------- kernel 5: out proj + residual + LN2 + coord update
__global__ __launch_bounds__(256) void out_kernel(
    const float* __restrict__ attn_out, const float* __restrict__ x,
    const float* __restrict__ coords,
    const float* __restrict__ Wo, const float* __restrict__ bo,
    const float* __restrict__ g2, const float* __restrict__ b2,
    float* __restrict__ out, float* __restrict__ coords_out) {
    const int row = blockIdx.x;
    const int t = threadIdx.x;
    __shared__ float sIn[CONCAT_];
    __shared__ float red[4];
    __shared__ float credp[2][3];

    const float* ar = attn_out + (size_t)row * CONCAT_;
    sIn[t] = ar[t]; sIn[t + 256] = ar[t + 256]; sIn[t + 512] = ar[t + 512];
    if (t < 128) sIn[t + 768] = ar[t + 768];
    __syncthreads();

    float c0 = 0.f, c1 = 0.f, c2 = 0.f;
    if (t < 128) { c0 = sIn[512 + t * 3]; c1 = sIn[512 + t * 3 + 1]; c2 = sIn[512 + t * 3 + 2]; }
#pragma unroll
    for (int o = 32; o; o >>= 1) {
        c0 += __shfl_down(c0, o, 64);
        c1 += __shfl_down(c1, o, 64);
        c2 += __shfl_down(c2, o, 64);
    }
    if (t < 128 && (t & 63) == 0) {
        credp[t >> 6][0] = c0; credp[t >> 6][1] = c1; credp[t >> 6][2] = c2;
    }
    __syncthreads();
    if (t < 3) {
        float s = credp[0][t] + credp[1][t];
        coords_out[row * 3 + t] = coords[row * 3 + t] + 0.1f * s * (1.0f / 128.f);
    }

    float a0 = bo[t], a1 = bo[t + 256];
    for (int i = 0; i < CONCAT_; i++) {
        float xi = sIn[i];
        a0 = fmaf(xi, Wo[i * D_ + t], a0);
        a1 = fmaf(xi, Wo[i * D_ + t + 256], a1);
    }
    float y0 = x[(size_t)row * D_ + t] + a0;
    float y1 = x[(size_t)row * D_ + t + 256] + a1;

    float s = waveReduceSum(y0 + y1);
    int lane = t & 63, wid = t >> 6;
    if (lane == 0) red[wid] = s;
    __syncthreads();
    float mean = (red[0] + red[1] + red[2] + red[3]) * (1.0f / D_);
    __syncthreads();
    float d0 = y0 - mean, d1 = y1 - mean;
    float vv = waveReduceSum(d0 * d0 + d1 * d1);
    if (lane == 0) red[wid] = vv;
    __syncthreads();
    float var = (red[0] + red[1] + red[2] + red[3]) * (1.0f / D_);
    float rs = rsqrtf(var + 1e-5f);
    out[(size_t)row * D_ + t]       = d0 * rs * g2[t] + b2[t];
    out[(size_t)row * D_ + t + 256] = d1 * rs * g2[t + 256] + b2[t + 256];
}

// ---------------------------------------------------------------- launch
extern "C" void kernel_launch(void* const* d_in, const int* in_sizes, int n_in,
                              void* d_out, int out_size, void* d_ws, size_t ws_size,
                              hipStream_t stream) {
    const float* x      = (const float*)d_in[0];
    const float* coords = (const float*)d_in[1];
    const float* Wq     = (const float*)d_in[2];
    const float* Wk     = (const float*)d_in[3];
    const float* Wv     = (const float*)d_in[4];
    const float* Wqp    = (const float*)d_in[5];
    const float* bqp    = (const float*)d_in[6];
    const float* Wkp    = (const float*)d_in[7];
    const float* bkp    = (const float*)d_in[8];
    const float* Wvp    = (const float*)d_in[9];
    const float* bvp    = (const float*)d_in[10];
    const float* Wd1    = (const float*)d_in[11];
    const float* bd1    = (const float*)d_in[12];
    const float* Wd2    = (const float*)d_in[13];
    const float* bd2    = (const float*)d_in[14];
    const float* Wo     = (const float*)d_in[15];
    const float* bo     = (const float*)d_in[16];
    const float* g1     = (const float*)d_in[17];
    const float* b1     = (const float*)d_in[18];
    const float* g2     = (const float*)d_in[19];
    const float* b2     = (const float*)d_in[20];

    float* out        = (float*)d_out;
    float* coords_out = (float*)d_out + (size_t)B_ * S_ * D_;

    float* ws = (float*)d_ws;
    const size_t NROW = (size_t)B_ * S_;
    float* xn   = ws;
    float* q    = xn   + NROW * D_;
    float* k    = q    + NROW * D_;
    float* v    = k    + NROW * D_;
    float* qp   = v    + NROW * D_;
    float* kp   = qp   + NROW * HP3_;
    float* vp   = kp   + NROW * HP3_;
    float* kn2  = vp   + NROW * HP3_;
    float* aout = kn2  + NROW * H_;

    ln1_kernel<<<NROW, 256, 0, stream>>>(x, g1, b1, xn);

    dim3 pgrid(2688 / 64, 2048 / 64);
    proj_kernel<<<pgrid, 256, 0, stream>>>(xn, coords, Wq, Wk, Wv,
                                           Wqp, bqp, Wkp, bkp, Wvp, bvp,
                                           q, k, v, qp, kp, vp);

    kn2_kernel<<<(NROW * H_) / 256, 256, 0, stream>>>(kp, kn2);

    dim3 agrid(S_ / QT, H_, B_);
    attn_kernel<<<agrid, 256, 0, stream>>>(q, k, v, qp, kp, vp, kn2, coords,
                                           Wd1, bd1, Wd2, bd2, aout);

    out_kernel<<<NROW, 256, 0, stream>>>(aout, x, coords, Wo, bo, g2, b2,
                                         out, coords_out);
}

// Round 7
// 492.896 us; speedup vs baseline: 2.0379x; 1.1753x over previous
//
#include <hip/hip_runtime.h>
#include <math.h>

#define B_ 2
#define S_ 1024
#define D_ 512
#define H_ 8
#define P_ 16
#define DH_ 64
#define HP3_ 384
#define CONCAT_ 896
#define CUTOFF 15.0f
#define SCALE_ 0.125f   // DH^-0.5 = 1/8
#define QT 32
#define KT 64
// LDS strides (floats), all multiples of 4 (float4-aligned), odd*4 for bank rotation
#define SQS 68
#define SQPS 52
#define SKS 68
#define SKPS 52
#define SVS 120
#define SWS 68

// ---------------------------------------------------------------- reductions
__device__ __forceinline__ float waveReduceSum(float v) {
#pragma unroll
    for (int o = 32; o; o >>= 1) v += __shfl_down(v, o, 64);
    return v;
}
__device__ __forceinline__ float dot4(float4 a, float4 b, float acc) {
    return fmaf(a.x, b.x, fmaf(a.y, b.y, fmaf(a.z, b.z, fmaf(a.w, b.w, acc))));
}

// ---------------------------------------------------------------- kernel 1: LN (used for LN1 and LN2)
__global__ __launch_bounds__(256) void ln1_kernel(
    const float* __restrict__ x, const float* __restrict__ g,
    const float* __restrict__ b, float* __restrict__ xn) {
    const int row = blockIdx.x;
    const int t = threadIdx.x;
    const float* xr = x + row * D_;
    float x0 = xr[t], x1 = xr[t + 256];
    __shared__ float red[4];
    float s = waveReduceSum(x0 + x1);
    int lane = t & 63, wid = t >> 6;
    if (lane == 0) red[wid] = s;
    __syncthreads();
    float mean = (red[0] + red[1] + red[2] + red[3]) * (1.0f / D_);
    __syncthreads();
    float d0 = x0 - mean, d1 = x1 - mean;
    float v = waveReduceSum(d0 * d0 + d1 * d1);
    if (lane == 0) red[wid] = v;
    __syncthreads();
    float var = (red[0] + red[1] + red[2] + red[3]) * (1.0f / D_);
    float rs = rsqrtf(var + 1e-5f);
    xn[row * D_ + t]       = d0 * rs * g[t] + b[t];
    xn[row * D_ + t + 256] = d1 * rs * g[t + 256] + b[t + 256];
}

// ---------------------------------------------------------------- kernel 2: projections GEMM
__global__ __launch_bounds__(256) void proj_kernel(
    const float* __restrict__ xn, const float* __restrict__ coords,
    const float* __restrict__ Wq, const float* __restrict__ Wk, const float* __restrict__ Wv,
    const float* __restrict__ Wqp, const float* __restrict__ bqp,
    const float* __restrict__ Wkp, const float* __restrict__ bkp,
    const float* __restrict__ Wvp, const float* __restrict__ bvp,
    float* __restrict__ q, float* __restrict__ k, float* __restrict__ v,
    float* __restrict__ qp, float* __restrict__ kp, float* __restrict__ vp) {
    const int tid = threadIdx.x;
    const int rowBase = blockIdx.y * 64;
    const int colBase = blockIdx.x * 64;

    const float* Wseg; int ldw, segBase, segId;
    if      (colBase < 512)  { Wseg = Wq;  ldw = D_;   segBase = 0;    segId = 0; }
    else if (colBase < 1024) { Wseg = Wk;  ldw = D_;   segBase = 512;  segId = 1; }
    else if (colBase < 1536) { Wseg = Wv;  ldw = D_;   segBase = 1024; segId = 2; }
    else if (colBase < 1920) { Wseg = Wqp; ldw = HP3_; segBase = 1536; segId = 3; }
    else if (colBase < 2304) { Wseg = Wkp; ldw = HP3_; segBase = 1920; segId = 4; }
    else                     { Wseg = Wvp; ldw = HP3_; segBase = 2304; segId = 5; }
    const int segc0 = colBase - segBase;

    __shared__ float As[16][65];
    __shared__ float Bs[16][64];
    const int tx = tid & 15, ty = tid >> 4;

    float acc[4][4];
#pragma unroll
    for (int i = 0; i < 4; i++)
#pragma unroll
        for (int j = 0; j < 4; j++) acc[i][j] = 0.f;

    for (int k0 = 0; k0 < D_; k0 += 16) {
#pragma unroll
        for (int i = 0; i < 4; i++) {
            int e = tid + i * 256;
            int r = e >> 4, kk = e & 15;
            As[kk][r] = xn[(rowBase + r) * D_ + k0 + kk];
            int c = e & 63, kb = e >> 6;
            Bs[kb][c] = Wseg[(k0 + kb) * ldw + segc0 + c];
        }
        __syncthreads();
#pragma unroll
        for (int kk = 0; kk < 16; kk++) {
            float a[4], bb[4];
#pragma unroll
            for (int i = 0; i < 4; i++) a[i] = As[kk][ty * 4 + i];
#pragma unroll
            for (int j = 0; j < 4; j++) bb[j] = Bs[kk][tx * 4 + j];
#pragma unroll
            for (int i = 0; i < 4; i++)
#pragma unroll
                for (int j = 0; j < 4; j++) acc[i][j] = fmaf(a[i], bb[j], acc[i][j]);
        }
        __syncthreads();
    }

#pragma unroll
    for (int i = 0; i < 4; i++) {
        int r = rowBase + ty * 4 + i;
#pragma unroll
        for (int j = 0; j < 4; j++) {
            int lc = segc0 + tx * 4 + j;
            float val = acc[i][j];
            switch (segId) {
                case 0: q[r * D_ + lc] = val; break;
                case 1: k[r * D_ + lc] = val; break;
                case 2: v[r * D_ + lc] = val; break;
                case 3: qp[r * HP3_ + lc] = val + bqp[lc] + coords[r * 3 + lc % 3]; break;
                case 4: kp[r * HP3_ + lc] = val + bkp[lc] + coords[r * 3 + lc % 3]; break;
                case 5: vp[r * HP3_ + lc] = val + bvp[lc]; break;
            }
        }
    }
}

// ---------------------------------------------------------------- kernel 3: kn2 = sum(kp^2) per (b,s,h)
__global__ __launch_bounds__(256) void kn2_kernel(
    const float* __restrict__ kp, float* __restrict__ kn2) {
    int idx = blockIdx.x * 256 + threadIdx.x;
    const float* p = kp + idx * 48;
    float s = 0.f;
#pragma unroll
    for (int i = 0; i < 48; i++) s = fmaf(p[i], p[i], s);
    kn2[idx] = s;
}

// ---------------------------------------------------------------- kernel 4: flash attention, float4 LDS micro-kernel
// Thread (qpair = tid>>4, sub = tid&15). Logits: 2q x 4k (keys sub+16j);
// PV: 2q x 8 dims (dims sub*8, sub<14). All inner LDS traffic is ds_read_b128.
__global__ __launch_bounds__(256, 2) void attn_kernel(
    const float* __restrict__ q, const float* __restrict__ k, const float* __restrict__ v,
    const float* __restrict__ qp, const float* __restrict__ kp, const float* __restrict__ vp,
    const float* __restrict__ kn2, const float* __restrict__ coords,
    const float* __restrict__ Wd1, const float* __restrict__ bd1,
    const float* __restrict__ Wd2, const float* __restrict__ bd2,
    float* __restrict__ attn_out) {
    const int qt = blockIdx.x, h = blockIdx.y, b = blockIdx.z;
    const int tid = threadIdx.x;
    const int qpair = tid >> 4;
    const int sub = tid & 15;
    const int q0 = qpair * 2, q1 = q0 + 1;
    const int qbase = qt * QT;

    __shared__ float sQ[QT * SQS];        // 32x68
    __shared__ float sQP[QT * SQPS];      // 32x52
    __shared__ float sKV[7680];           // K[64][68]@0 + KP[64][52]@4352  |  V[64][120]@0
    __shared__ float sWt[QT * SWS];       // [q][k] 32x68
    __shared__ float sCq[QT * 3], sCk[KT * 3];
    __shared__ float sKn2[KT], sQn2[QT];
    __shared__ float sM[QT], sL[QT], sTm[QT];
    __shared__ float sW1[32], sB1[32], sW2h[32];

    const size_t bq = (size_t)(b * S_ + qbase);
    // ---- stage Q-side (once)
#pragma unroll
    for (int i = 0; i < 2; i++) {
        int f4 = tid + i * 256;           // 512 = 32x16
        int r = f4 >> 4, c = f4 & 15;
        *(float4*)&sQ[r * SQS + c * 4] = *(const float4*)(q + (bq + r) * D_ + h * DH_ + c * 4);
    }
    {
        int f4 = tid;                     // 384 = 32x12 (first 256 here, rest below)
        int r = f4 / 12, c = f4 % 12;
        *(float4*)&sQP[r * SQPS + c * 4] = *(const float4*)(qp + (bq + r) * HP3_ + h * 48 + c * 4);
        if (tid < 128) {
            int f42 = tid + 256;
            int r2 = f42 / 12, c2 = f42 % 12;
            *(float4*)&sQP[r2 * SQPS + c2 * 4] = *(const float4*)(qp + (bq + r2) * HP3_ + h * 48 + c2 * 4);
        }
    }
    if (tid < QT * 3) sCq[tid] = coords[bq * 3 + tid];
    if (tid >= 128 && tid < 160) sW1[tid - 128] = Wd1[tid - 128];
    else if (tid < 192 && tid >= 160) sB1[tid - 160] = bd1[tid - 160];
    else if (tid >= 192 && tid < 224) sW2h[tid - 192] = Wd2[(tid - 192) * H_ + h];
    else if (tid >= 224) { int t2 = tid - 224; sM[t2] = -3.0e38f; sL[t2] = 0.f; }
    __syncthreads();
    if (tid < QT) {
        float s = 0.f;
#pragma unroll
        for (int i = 0; i < 48; i++) s = fmaf(sQP[tid * SQPS + i], sQP[tid * SQPS + i], s);
        sQn2[tid] = s;
    }
    const float bd2h = bd2[h];

    float o0[8] = {0,0,0,0,0,0,0,0}, o1[8] = {0,0,0,0,0,0,0,0};
    const int db = sub * 8;               // PV dims (sub<14)

    for (int kt = 0; kt < S_ / KT; kt++) {
        const size_t bk = (size_t)(b * S_ + kt * KT);
        // ---- stage K + KP
#pragma unroll
        for (int i = 0; i < 4; i++) {
            int f4 = tid + i * 256;       // 1024 = 64x16
            int r = f4 >> 4, c = f4 & 15;
            *(float4*)&sKV[r * SKS + c * 4] = *(const float4*)(k + (bk + r) * D_ + h * DH_ + c * 4);
        }
#pragma unroll
        for (int i = 0; i < 3; i++) {
            int f4 = tid + i * 256;       // 768 = 64x12
            int r = f4 / 12, c = f4 % 12;
            *(float4*)&sKV[4352 + r * SKPS + c * 4] = *(const float4*)(kp + (bk + r) * HP3_ + h * 48 + c * 4);
        }
        if (tid < KT) sKn2[tid] = kn2[(bk + tid) * H_ + h];
        if (tid < KT * 3) sCk[tid] = coords[bk * 3 + tid];
        __syncthreads();                  // SYNC-K

        // ---- distances (2q x 4k, keys sub+16j)
        float ds0[4], ds1[4];
        {
            const float qx0 = sCq[q0*3], qy0 = sCq[q0*3+1], qz0 = sCq[q0*3+2];
            const float qx1 = sCq[q1*3], qy1 = sCq[q1*3+1], qz1 = sCq[q1*3+2];
#pragma unroll
            for (int j = 0; j < 4; j++) {
                int kk = sub + 16 * j;
                float kx = sCk[kk*3], ky = sCk[kk*3+1], kz = sCk[kk*3+2];
                float dx = qx0-kx, dy = qy0-ky, dz = qz0-kz;
                ds0[j] = sqrtf(fmaf(dx,dx,fmaf(dy,dy,dz*dz)));
                dx = qx1-kx; dy = qy1-ky; dz = qz1-kz;
                ds1[j] = sqrtf(fmaf(dx,dx,fmaf(dy,dy,dz*dz)));
            }
        }
        // ---- dist-MLP bias (pd folded in below)
        float bias0[4], bias1[4];
#pragma unroll
        for (int j = 0; j < 4; j++) { bias0[j] = bd2h; bias1[j] = bd2h; }
#pragma unroll 4
        for (int jj = 0; jj < 32; jj++) {
            float w1 = sW1[jj], bb = sB1[jj], w2 = sW2h[jj];
#pragma unroll
            for (int j = 0; j < 4; j++) {
                float h0 = fmaf(ds0[j], w1, bb);
                float h1 = fmaf(ds1[j], w1, bb);
                bias0[j] = fmaf(fmaxf(h0, 0.f), w2, bias0[j]);
                bias1[j] = fmaf(fmaxf(h1, 0.f), w2, bias1[j]);
            }
        }
        // ---- qk dot via float4 (2q x 4k x 4d per iter)
        float d0a[4] = {0,0,0,0}, d1a[4] = {0,0,0,0};
#pragma unroll 4
        for (int d4 = 0; d4 < 16; d4++) {
            float4 a0 = *(const float4*)&sQ[q0 * SQS + d4 * 4];
            float4 a1 = *(const float4*)&sQ[q1 * SQS + d4 * 4];
#pragma unroll
            for (int j = 0; j < 4; j++) {
                float4 bv = *(const float4*)&sKV[(sub + 16 * j) * SKS + d4 * 4];
                d0a[j] = dot4(a0, bv, d0a[j]);
                d1a[j] = dot4(a1, bv, d1a[j]);
            }
        }
        // ---- point dot via float4, folded into bias
#pragma unroll 4
        for (int d4 = 0; d4 < 12; d4++) {
            float4 a0 = *(const float4*)&sQP[q0 * SQPS + d4 * 4];
            float4 a1 = *(const float4*)&sQP[q1 * SQPS + d4 * 4];
#pragma unroll
            for (int j = 0; j < 4; j++) {
                float4 bv = *(const float4*)&sKV[4352 + (sub + 16 * j) * SKPS + d4 * 4];
                bias0[j] = dot4(a0, bv, bias0[j]);
                bias1[j] = dot4(a1, bv, bias1[j]);
            }
        }
        // ---- logits + mask
        const float qn20 = sQn2[q0], qn21 = sQn2[q1];
        float lg0[4], lg1[4];
#pragma unroll
        for (int j = 0; j < 4; j++) {
            float kn = sKn2[sub + 16 * j];
            float v0 = fmaf(SCALE_, d0a[j], bias0[j]) - 0.5f * (qn20 + kn);
            float v1 = fmaf(SCALE_, d1a[j], bias1[j]) - 0.5f * (qn21 + kn);
            lg0[j] = (ds0[j] < CUTOFF) ? v0 : -1e9f;
            lg1[j] = (ds1[j] < CUTOFF) ? v1 : -1e9f;
        }
        // ---- tile row-max across the 16 key lanes
        float t0 = fmaxf(fmaxf(lg0[0], lg0[1]), fmaxf(lg0[2], lg0[3]));
        float t1 = fmaxf(fmaxf(lg1[0], lg1[1]), fmaxf(lg1[2], lg1[3]));
#pragma unroll
        for (int off = 1; off < 16; off <<= 1) {
            t0 = fmaxf(t0, __shfl_xor(t0, off, 16));
            t1 = fmaxf(t1, __shfl_xor(t1, off, 16));
        }
        if (sub == 0) { sTm[q0] = t0; sTm[q1] = t1; }
        __syncthreads();                  // SYNC-A1
        const float m0o = sM[q0], m1o = sM[q1];
        const float nm0 = fmaxf(m0o, sTm[q0]), nm1 = fmaxf(m1o, sTm[q1]);
        const float sc0 = __expf(m0o - nm0), sc1 = __expf(m1o - nm1);
        float ps0 = 0.f, ps1 = 0.f;
#pragma unroll
        for (int j = 0; j < 4; j++) {
            float w0 = __expf(lg0[j] - nm0);
            float w1 = __expf(lg1[j] - nm1);
            sWt[q0 * SWS + sub + 16 * j] = w0;
            sWt[q1 * SWS + sub + 16 * j] = w1;
            ps0 += w0; ps1 += w1;
        }
#pragma unroll
        for (int off = 1; off < 16; off <<= 1) {
            ps0 += __shfl_xor(ps0, off, 16);
            ps1 += __shfl_xor(ps1, off, 16);
        }
        __syncthreads();                  // SYNC-A2
        if (sub == 0) {
            sM[q0] = nm0; sM[q1] = nm1;
            sL[q0] = sL[q0] * sc0 + ps0;
            sL[q1] = sL[q1] * sc1 + ps1;
        }
        // ---- stage V (overlays K/KP region; all K/KP reads done pre-SYNC-A1)
        {
            int r = tid >> 2, cb = (tid & 3) * 7;
#pragma unroll
            for (int i = 0; i < 7; i++) {
                int c4 = cb + i;          // 0..27 float4s of the 112-float row
                float4 t;
                if (c4 < 16) t = *(const float4*)(v  + (bk + r) * D_   + h * DH_ + c4 * 4);
                else         t = *(const float4*)(vp + (bk + r) * HP3_ + h * 48  + (c4 - 16) * 4);
                *(float4*)&sKV[r * SVS + c4 * 4] = t;
            }
        }
        __syncthreads();                  // SYNC-B
        // ---- PV: 2q x 8 dims, iterate 64 keys (all b128 reads)
        if (sub < 14) {
#pragma unroll
            for (int j = 0; j < 8; j++) { o0[j] *= sc0; o1[j] *= sc1; }
            for (int kk4 = 0; kk4 < 16; kk4++) {
                float w0a[4], w1a[4];
                *(float4*)w0a = *(const float4*)&sWt[q0 * SWS + kk4 * 4];
                *(float4*)w1a = *(const float4*)&sWt[q1 * SWS + kk4 * 4];
#pragma unroll
                for (int jj = 0; jj < 4; jj++) {
                    int kk = kk4 * 4 + jj;
                    float4 va = *(const float4*)&sKV[kk * SVS + db];
                    float4 vb = *(const float4*)&sKV[kk * SVS + db + 4];
                    o0[0] = fmaf(w0a[jj], va.x, o0[0]); o0[1] = fmaf(w0a[jj], va.y, o0[1]);
                    o0[2] = fmaf(w0a[jj], va.z, o0[2]); o0[3] = fmaf(w0a[jj], va.w, o0[3]);
                    o0[4] = fmaf(w0a[jj], vb.x, o0[4]); o0[5] = fmaf(w0a[jj], vb.y, o0[5]);
                    o0[6] = fmaf(w0a[jj], vb.z, o0[6]); o0[7] = fmaf(w0a[jj], vb.w, o0[7]);
                    o1[0] = fmaf(w1a[jj], va.x, o1[0]); o1[1] = fmaf(w1a[jj], va.y, o1[1]);
                    o1[2] = fmaf(w1a[jj], va.z, o1[2]); o1[3] = fmaf(w1a[jj], va.w, o1[3]);
                    o1[4] = fmaf(w1a[jj], vb.x, o1[4]); o1[5] = fmaf(w1a[jj], vb.y, o1[5]);
                    o1[6] = fmaf(w1a[jj], vb.z, o1[6]); o1[7] = fmaf(w1a[jj], vb.w, o1[7]);
                }
            }
        }
        __syncthreads();                  // SYNC-C (before next K-stage overwrites sKV)
    }

    // ---- epilogue
    if (sub < 14) {
        const float il0 = 1.0f / sL[q0], il1 = 1.0f / sL[q1];
        const int off = (db < 64) ? (h * 64 + db) : (512 + h * 48 + (db - 64));
        float* r0 = attn_out + (size_t)(bq + q0) * CONCAT_ + off;
        float* r1 = attn_out + (size_t)(bq + q1) * CONCAT_ + off;
        float4 w0a, w0b, w1a, w1b;
        w0a.x=o0[0]*il0; w0a.y=o0[1]*il0; w0a.z=o0[2]*il0; w0a.w=o0[3]*il0;
        w0b.x=o0[4]*il0; w0b.y=o0[5]*il0; w0b.z=o0[6]*il0; w0b.w=o0[7]*il0;
        w1a.x=o1[0]*il1; w1a.y=o1[1]*il1; w1a.z=o1[2]*il1; w1a.w=o1[3]*il1;
        w1b.x=o1[4]*il1; w1b.y=o1[5]*il1; w1b.z=o1[6]*il1; w1b.w=o1[7]*il1;
        *(float4*)r0 = w0a; *(float4*)(r0 + 4) = w0b;
        *(float4*)r1 = w1a; *(float4*)(r1 + 4) = w1b;
    }
}

// ---------------------------------------------------------------- kernel 5: out projection GEMM (+bias+residual)
// yres = aout(2048x896) @ Wo(896x512) + bo + x   -> then ln1_kernel does LN2.
__global__ __launch_bounds__(256) void ogemm_kernel(
    const float* __restrict__ aout, const float* __restrict__ x,
    const float* __restrict__ Wo, const float* __restrict__ bo,
    float* __restrict__ yres) {
    const int tid = threadIdx.x;
    const int rowBase = blockIdx.y * 64;
    const int colBase = blockIdx.x * 64;

    __shared__ float As[16][65];
    __shared__ float Bs[16][64];
    const int tx = tid & 15, ty = tid >> 4;

    float acc[4][4];
#pragma unroll
    for (int i = 0; i < 4; i++)
#pragma unroll
        for (int j = 0; j < 4; j++) acc[i][j] = 0.f;

    for (int k0 = 0; k0 < CONCAT_; k0 += 16) {
#pragma unroll
        for (int i = 0; i < 4; i++) {
            int e = tid + i * 256;
            int r = e >> 4, kk = e & 15;
            As[kk][r] = aout[(size_t)(rowBase + r) * CONCAT_ + k0 + kk];
            int c = e & 63, kb = e >> 6;
            Bs[kb][c] = Wo[(k0 + kb) * D_ + colBase + c];
        }
        __syncthreads();
#pragma unroll
        for (int kk = 0; kk < 16; kk++) {
            float a[4], bb[4];
#pragma unroll
            for (int i = 0; i < 4; i++) a[i] = As[kk][ty * 4 + i];
#pragma unroll
            for (int j = 0; j < 4; j++) bb[j] = Bs[kk][tx * 4 + j];
#pragma unroll
            for (int i = 0; i < 4; i++)
#pragma unroll
                for (int j = 0; j < 4; j++) acc[i][j] = fmaf(a[i], bb[j], acc[i][j]);
        }
        __syncthreads();
    }

#pragma unroll
    for (int i = 0; i < 4; i++) {
        int r = rowBase + ty * 4 + i;
#pragma unroll
        for (int j = 0; j < 4; j++) {
            int lc = colBase + tx * 4 + j;
            yres[(size_t)r * D_ + lc] = acc[i][j] + bo[lc] + x[(size_t)r * D_ + lc];
        }
    }
}

// ---------------------------------------------------------------- kernel 6: coord update
__global__ __launch_bounds__(64) void coord_kernel(
    const float* __restrict__ aout, const float* __restrict__ coords,
    float* __restrict__ coords_out) {
    const int row = blockIdx.x;
    const int t = threadIdx.x;
    const float* ap = aout + (size_t)row * CONCAT_ + 512;
    float c0 = ap[t * 3]     + ap[(t + 64) * 3];
    float c1 = ap[t * 3 + 1] + ap[(t + 64) * 3 + 1];
    float c2 = ap[t * 3 + 2] + ap[(t + 64) * 3 + 2];
#pragma unroll
    for (int o = 32; o; o >>= 1) {
        c0 += __shfl_down(c0, o, 64);
        c1 += __shfl_down(c1, o, 64);
        c2 += __shfl_down(c2, o, 64);
    }
    if (t == 0) {
        coords_out[row * 3 + 0] = coords[row * 3 + 0] + c0 * (0.1f / 128.f);
        coords_out[row * 3 + 1] = coords[row * 3 + 1] + c1 * (0.1f / 128.f);
        coords_out[row * 3 + 2] = coords[row * 3 + 2] + c2 * (0.1f / 128.f);
    }
}

// ---------------------------------------------------------------- launch
extern "C" void kernel_launch(void* const* d_in, const int* in_sizes, int n_in,
                              void* d_out, int out_size, void* d_ws, size_t ws_size,
                              hipStream_t stream) {
    const float* x      = (const float*)d_in[0];
    const float* coords = (const float*)d_in[1];
    const float* Wq     = (const float*)d_in[2];
    const float* Wk     = (const float*)d_in[3];
    const float* Wv     = (const float*)d_in[4];
    const float* Wqp    = (const float*)d_in[5];
    const float* bqp    = (const float*)d_in[6];
    const float* Wkp    = (const float*)d_in[7];
    const float* bkp    = (const float*)d_in[8];
    const float* Wvp    = (const float*)d_in[9];
    const float* bvp    = (const float*)d_in[10];
    const float* Wd1    = (const float*)d_in[11];
    const float* bd1    = (const float*)d_in[12];
    const float* Wd2    = (const float*)d_in[13];
    const float* bd2    = (const float*)d_in[14];
    const float* Wo     = (const float*)d_in[15];
    const float* bo     = (const float*)d_in[16];
    const float* g1     = (const float*)d_in[17];
    const float* b1     = (const float*)d_in[18];
    const float* g2     = (const float*)d_in[19];
    const float* b2     = (const float*)d_in[20];

    float* out        = (float*)d_out;
    float* coords_out = (float*)d_out + (size_t)B_ * S_ * D_;

    float* ws = (float*)d_ws;
    const size_t NROW = (size_t)B_ * S_;
    float* xn   = ws;                    // also reused as yres after proj
    float* q    = xn   + NROW * D_;
    float* k    = q    + NROW * D_;
    float* v    = k    + NROW * D_;
    float* qp   = v    + NROW * D_;
    float* kp   = qp   + NROW * HP3_;
    float* vp   = kp   + NROW * HP3_;
    float* kn2  = vp   + NROW * HP3_;
    float* aout = kn2  + NROW * H_;

    ln1_kernel<<<NROW, 256, 0, stream>>>(x, g1, b1, xn);

    dim3 pgrid(2688 / 64, 2048 / 64);
    proj_kernel<<<pgrid, 256, 0, stream>>>(xn, coords, Wq, Wk, Wv,
                                           Wqp, bqp, Wkp, bkp, Wvp, bvp,
                                           q, k, v, qp, kp, vp);

    kn2_kernel<<<(NROW * H_) / 256, 256, 0, stream>>>(kp, kn2);

    dim3 agrid(S_ / QT, H_, B_);
    attn_kernel<<<agrid, 256, 0, stream>>>(q, k, v, qp, kp, vp, kn2, coords,
                                           Wd1, bd1, Wd2, bd2, aout);

    float* yres = xn;   // xn is dead after proj_kernel
    dim3 ogrid(D_ / 64, 2048 / 64);
    ogemm_kernel<<<ogrid, 256, 0, stream>>>(aout, x, Wo, bo, yres);

    ln1_kernel<<<NROW, 256, 0, stream>>>(yres, g2, b2, out);

    coord_kernel<<<NROW, 64, 0, stream>>>(aout, coords, coords_out);
}